// Round 9
// baseline (1866.450 us; speedup 1.0000x reference)
//
#include <hip/hip_runtime.h>

// HierarchicalGraphNet: N=100000 nodes, E=320000 edges, D=256, L=3, G=4096.
#define N_NODES 100000
#define N_EDGES 320000
#define N_GRAPH 4096
#define M_PAD   100096                   // N padded to multiple of 128
#define N_TILES 782                      // M_PAD / 128
#define LN_EPS  1e-5f
#define S_EL    ((size_t)M_PAD * 256)    // elements per full M x 256 plane
#define CAP     32                       // in-edge bucket capacity per node

typedef __attribute__((ext_vector_type(8))) short short8;   // 8 x bf16 MFMA operand
typedef __attribute__((ext_vector_type(4))) float f32x4;    // MFMA accumulator
typedef unsigned short u16;

__device__ __forceinline__ float bf2f(u16 u){
  return __uint_as_float(((unsigned)u) << 16);
}
__device__ __forceinline__ u16 f2bf(float f){   // RNE round
  unsigned u = __float_as_uint(f);
  return (u16)((u + 0x7FFFu + ((u >> 16) & 1u)) >> 16);
}
// external float tensor read: fp32 or bf16 per runtime flag
__device__ __forceinline__ float ldext(const void* p, long i, bool f32){
  return f32 ? ((const float*)p)[i] : bf2f(((const u16*)p)[i]);
}
__device__ __forceinline__ float sigm(float x){ return 1.0f/(1.0f + __expf(-x)); }

// swizzled byte offset inside one A-tile (rows x 256 bf16, row=512B)
// XOR row bits into byte-addr bits [4..6]: breaks row-strided ds_read_b128
// bank conflicts (G4), bijective per 8-row stripe.
__device__ __forceinline__ int swzb(int row, int colByte){
  return (row << 9) + (colByte ^ ((row & 7) << 4));
}

// ---- dtype detector ---------------------------------------------------------
__global__ void k_detect(const unsigned* __restrict__ x32, int* __restrict__ flag){
  unsigned u = x32[threadIdx.x];            // 64 threads
  int ef = (int)((u >> 23) & 0xFFu);
  int ok = (ef >= 64 && ef <= 190) ? 1 : 0;
  #pragma unroll
  for (int o=1; o<64; o<<=1) ok += __shfl_xor(ok, o);
  if (threadIdx.x == 0) *flag = (ok >= 32) ? 1 : 0;
}

// ---- weight pre-conversion to bf16 (runs once, removes f32 from hot loops) --
__global__ void k_wconv(const void* __restrict__ src, u16* __restrict__ dst,
                        const int* __restrict__ dflag){
  const bool f32 = (*dflag != 0);
  size_t base = ((size_t)blockIdx.x*256 + threadIdx.x)*8;
  if (f32){
    const float* s = (const float*)src + base;
    float4 a = *(const float4*)s;
    float4 b = *(const float4*)(s + 4);
    ushort4 lo = make_ushort4(f2bf(a.x),f2bf(a.y),f2bf(a.z),f2bf(a.w));
    ushort4 hi = make_ushort4(f2bf(b.x),f2bf(b.y),f2bf(b.z),f2bf(b.w));
    uint4 v;
    v.x = (unsigned)lo.x | ((unsigned)lo.y<<16);
    v.y = (unsigned)lo.z | ((unsigned)lo.w<<16);
    v.z = (unsigned)hi.x | ((unsigned)hi.y<<16);
    v.w = (unsigned)hi.z | ((unsigned)hi.w<<16);
    *(uint4*)&dst[base] = v;
  } else {
    *(uint4*)&dst[base] = *(const uint4*)((const u16*)src + base);
  }
}

// ---- init kernels -----------------------------------------------------------
__global__ void k_h_init(const void* __restrict__ x, u16* __restrict__ h,
                         const int* __restrict__ dflag){
  const bool f32 = (*dflag != 0);
  int i = blockIdx.x*256 + threadIdx.x;     // 8 elements per thread
  size_t base = (size_t)i*8;
  int n = (int)(base >> 8);
  uint4 v = make_uint4(0,0,0,0);
  if (n < N_NODES){
    if (f32){
      const float* xf = (const float*)x + base;
      float4 a = *(const float4*)xf;
      float4 b = *(const float4*)(xf + 4);
      ushort4 lo = make_ushort4(f2bf(a.x),f2bf(a.y),f2bf(a.z),f2bf(a.w));
      ushort4 hi = make_ushort4(f2bf(b.x),f2bf(b.y),f2bf(b.z),f2bf(b.w));
      v.x = (unsigned)lo.x | ((unsigned)lo.y<<16);
      v.y = (unsigned)lo.z | ((unsigned)lo.w<<16);
      v.z = (unsigned)hi.x | ((unsigned)hi.y<<16);
      v.w = (unsigned)hi.z | ((unsigned)hi.w<<16);
    } else {
      v = *(const uint4*)((const u16*)x + base);
    }
  }
  *(uint4*)&h[base] = v;
}

// ---- inverse-CSR bucket build (edges are static across layers) --------------
__global__ void k_bucket_build(const int* __restrict__ ei, int* __restrict__ cnt,
                               int* __restrict__ bucket, int* __restrict__ ovf,
                               int* __restrict__ ovfcnt){
  int e = blockIdx.x*256 + threadIdx.x;
  if (e >= N_EDGES) return;
  int s = ei[e];
  int d = ei[N_EDGES + e];
  int pos = atomicAdd(&cnt[d], 1);
  if (pos < CAP) bucket[(size_t)d*CAP + pos] = s;
  else { int o = atomicAdd(ovfcnt, 1); ovf[o] = e; }  // o < E always
}

// ---- atomic-free GIN aggregation: G[n] = h[n] + sum_{s->n} h[s] -------------
__global__ __launch_bounds__(256) void k_gather(
    const unsigned* __restrict__ h32, const int* __restrict__ cnt,
    const int* __restrict__ bucket, unsigned* __restrict__ G32)
{
  int gid = blockIdx.x*256 + threadIdx.x;
  int n = gid >> 7;                          // 2 rows per block
  int j = gid & 127;
  unsigned hv = h32[(size_t)n*128 + j];      // pad rows are zero
  float lo = bf2f((u16)(hv & 0xFFFFu));
  float hi = bf2f((u16)(hv >> 16));
  int c = (n < N_NODES) ? min(cnt[n], CAP) : 0;
  const int* bk = &bucket[(size_t)n*CAP];
  for (int k = 0; k < c; k++){
    int s = bk[k];
    unsigned v = h32[(size_t)s*128 + j];
    lo += bf2f((u16)(v & 0xFFFFu));
    hi += bf2f((u16)(v >> 16));
  }
  G32[(size_t)n*128 + j] = (unsigned)f2bf(lo) | ((unsigned)f2bf(hi) << 16);
}

// ---- overflow fallback (normally a no-op) -----------------------------------
__global__ void k_ovf_scatter(const unsigned* __restrict__ h32,
                              const int* __restrict__ ei,
                              const int* __restrict__ ovf,
                              const int* __restrict__ ovfcnt,
                              unsigned* __restrict__ G32){
  const long work = (long)(*ovfcnt) * 128;
  for (long i = (long)blockIdx.x*256 + threadIdx.x; i < work;
       i += (long)gridDim.x*256){
    int e = ovf[i >> 7];
    int j = (int)(i & 127);
    int s = ei[e];
    int d = ei[N_EDGES + e];
    unsigned sv = h32[(size_t)s*128 + j];
    float vlo = bf2f((u16)(sv & 0xFFFFu));
    float vhi = bf2f((u16)(sv >> 16));
    unsigned* addr = &G32[(size_t)d*128 + j];
    unsigned old = *addr;
    while (true){
      unsigned assumed = old;
      u16 nl = f2bf(bf2f((u16)(assumed & 0xFFFFu)) + vlo);
      u16 nh = f2bf(bf2f((u16)(assumed >> 16)) + vhi);
      unsigned nv = (unsigned)nl | ((unsigned)nh << 16);
      old = atomicCAS(addr, assumed, nv);
      if (old == assumed) break;
    }
  }
}

// ---- shared pieces for the fused MFMA kernels (256-thread blocks) -----------
// stage one 64x256 bf16 tile global->LDS, swizzled, fully coalesced
__device__ __forceinline__ void stage_tile64(const u16* __restrict__ g,
                                             u16* __restrict__ tile,
                                             size_t rowBase, int tid){
  #pragma unroll
  for (int j=0;j<8;j++){
    int cid = j*256 + tid;               // 2048 16B chunks
    int r  = cid >> 5;
    int cb = (cid & 31) << 4;            // colByte
    uint4 v = *(const uint4*)((const char*)g + (((rowBase + r) << 9) + cb));
    *(uint4*)((char*)tile + swzb(r, cb)) = v;
  }
}

// same, but applies per-column BatchNorm (ss[2c]=scale, ss[2c+1]=shift)
__device__ __forceinline__ void stage_tile64_bn(const u16* __restrict__ g,
                                                u16* __restrict__ tile,
                                                size_t rowBase, int tid,
                                                const float* __restrict__ ss){
  #pragma unroll
  for (int j=0;j<8;j++){
    int cid = j*256 + tid;
    int r  = cid >> 5;
    int cb = (cid & 31) << 4;            // colByte; bf16 col0 = cb/2
    uint4 v = *(const uint4*)((const char*)g + (((rowBase + r) << 9) + cb));
    unsigned vv[4] = {v.x, v.y, v.z, v.w};
    uint4 o;
    unsigned* op = (unsigned*)&o;
    #pragma unroll
    for (int q=0;q<4;q++){
      float4 s2 = *(const float4*)&ss[cb + q*4];   // sc0,sh0,sc1,sh1
      float x0 = bf2f((u16)(vv[q] & 0xFFFFu))*s2.x + s2.y;
      float x1 = bf2f((u16)(vv[q] >> 16))    *s2.z + s2.w;
      op[q] = (unsigned)f2bf(x0) | ((unsigned)f2bf(x1) << 16);
    }
    *(uint4*)((char*)tile + swzb(r, cb)) = o;
  }
}

// barrier-free K-loop: A from LDS tile(s), B (bf16 weights) from global/L2.
// Wave owns a 64x64 output tile: acc[4][4] fragments of 16x16.
// Per kk-step: 4 A-reads + 4 B-loads feed 16 MFMAs -> MFMA-issue-bound.
template<int KT>
__device__ __forceinline__ void gate_gemm(
    f32x4 (&acc)[4][4], const u16* __restrict__ tA1, const u16* __restrict__ tA2,
    const u16* __restrict__ W1, const u16* __restrict__ W2,
    int wc, int fr, int quad)
{
  constexpr int NH = KT/256;
  #pragma unroll
  for (int h2=0; h2<NH; h2++){
    const u16* tA = h2 ? tA2 : tA1;
    const u16* Wv = h2 ? W2  : W1;
    #pragma unroll
    for (int kk=0; kk<256; kk+=32){
      short8 af[4], bf[4];
      #pragma unroll
      for (int mi=0;mi<4;mi++)
        af[mi] = *(const short8*)((const char*)tA + swzb(mi*16 + fr, kk*2 + quad*16));
      #pragma unroll
      for (int ni=0;ni<4;ni++)
        bf[ni] = *(const short8*)&Wv[(size_t)(wc + ni*16 + fr)*256 + kk + quad*8];
      #pragma unroll
      for (int mi=0;mi<4;mi++)
        #pragma unroll
        for (int ni=0;ni<4;ni++)
          acc[mi][ni] = __builtin_amdgcn_mfma_f32_16x16x32_bf16(af[mi], bf[ni], acc[mi][ni], 0, 0, 0);
    }
  }
}

#define ZERO_ACC44(a) { f32x4 _z = {0.f,0.f,0.f,0.f}; \
  _Pragma("unroll") for (int _i=0;_i<4;_i++) \
  _Pragma("unroll") for (int _j=0;_j<4;_j++) a[_i][_j] = _z; }

// ---- fused GIN MLP: G = relu(relu(G@W1^T+b1)@W2^T+b2), + BN partial sums ----
// 256 threads, 4 waves (each 64 rows x 64 cols), block = 64 rows x 256 cols.
__global__ __launch_bounds__(256, 1) void k_mlp(
    u16* __restrict__ Gp,
    const u16* __restrict__ w1, const void* __restrict__ b1,
    const u16* __restrict__ w2, const void* __restrict__ b2,
    long bO, float* __restrict__ bns, const int* __restrict__ dflag)
{
  const bool f32 = (*dflag != 0);
  __shared__ u16 Ag[64*256];
  __shared__ u16 At[64*256];
  const int tid = threadIdx.x;
  const size_t rowBase = (size_t)blockIdx.x * 64;
  const int lane = tid & 63, wave = tid >> 6;
  const int wc = wave * 64;
  const int fr = lane & 15, quad = lane >> 4;

  stage_tile64(Gp, Ag, rowBase, tid);
  __syncthreads();

  f32x4 acc[4][4];
  ZERO_ACC44(acc);
  gate_gemm<256>(acc, Ag, nullptr, w1, nullptr, wc, fr, quad);

  // t = relu(acc + b1) -> LDS (swizzled, same layout as Ag)
  #pragma unroll
  for (int ni=0;ni<4;ni++){
    const int col = wc + ni*16 + fr;
    const float bv = ldext(b1, bO + col, f32);
    #pragma unroll
    for (int mi=0;mi<4;mi++)
      #pragma unroll
      for (int r4=0;r4<4;r4++){
        const int row = mi*16 + quad*4 + r4;
        float v = fmaxf(acc[mi][ni][r4] + bv, 0.f);
        *(u16*)((char*)At + swzb(row, col*2)) = f2bf(v);
      }
  }
  __syncthreads();

  ZERO_ACC44(acc);
  gate_gemm<256>(acc, At, nullptr, w2, nullptr, wc, fr, quad);

  // g = relu(acc + b2) -> global, plus per-column BN partial sums
  #pragma unroll
  for (int ni=0;ni<4;ni++){
    const int col = wc + ni*16 + fr;
    const float bv = ldext(b2, bO + col, f32);
    float s1 = 0.f, s2 = 0.f;
    #pragma unroll
    for (int mi=0;mi<4;mi++)
      #pragma unroll
      for (int r4=0;r4<4;r4++){
        const int row = mi*16 + quad*4 + r4;
        const size_t grow = rowBase + row;
        float v = fmaxf(acc[mi][ni][r4] + bv, 0.f);
        Gp[grow*256 + col] = f2bf(v);
        if (grow < N_NODES){ s1 += v; s2 += v*v; }
      }
    s1 += __shfl_xor(s1, 16); s1 += __shfl_xor(s1, 32);   // reduce over quad
    s2 += __shfl_xor(s2, 16); s2 += __shfl_xor(s2, 32);
    if (quad == 0){
      unsafeAtomicAdd(&bns[col],       s1);
      unsafeAtomicAdd(&bns[256 + col], s2);
    }
  }
}

// ---- finalize BN stats -> per-column scale/shift ----------------------------
__global__ void k_bn_fin(const float* __restrict__ sums,
                         const void* __restrict__ gam, const void* __restrict__ bet,
                         long gO, float* __restrict__ ss,
                         const int* __restrict__ dflag){
  const bool f32 = (*dflag != 0);
  int c = threadIdx.x;                     // 256 threads
  float mu  = sums[c] * (1.f/N_NODES);
  float var = sums[256 + c] * (1.f/N_NODES) - mu*mu;
  float sc  = ldext(gam, gO + c, f32) * rsqrtf(fmaxf(var, 0.f) + LN_EPS);
  ss[2*c]     = sc;
  ss[2*c + 1] = ldext(bet, gO + c, f32) - mu*sc;
}

// ---- fused GRU + LayerNorm: hout = LN((1-z)*tanh(gn + r*hn) + z*h) ----------
// 4 single-acc passes (R5 structure) with 64x64 wave tiles, 256 threads.
__global__ __launch_bounds__(256, 1) void k_gru(
    const u16* __restrict__ Gp, const u16* __restrict__ hp,
    const u16* __restrict__ wihl, const u16* __restrict__ whhl,
    const void* __restrict__ bih, const void* __restrict__ bhh, long bo,
    const void* __restrict__ lng, const void* __restrict__ lnb,
    const float* __restrict__ ss, u16* __restrict__ hout,
    const int* __restrict__ dflag)
{
  const bool f32 = (*dflag != 0);
  __shared__ u16 Ag[64*256];
  __shared__ u16 Ah[64*256];
  const int tid = threadIdx.x;
  const size_t rowBase = (size_t)blockIdx.x * 64;
  const int lane = tid & 63, wave = tid >> 6;
  const int wc = wave * 64;
  const int fr = lane & 15, quad = lane >> 4;

  stage_tile64_bn(Gp, Ag, rowBase, tid, ss);   // Ag = BN(G)  (g input)
  stage_tile64(hp, Ah, rowBase, tid);
  __syncthreads();

  f32x4 acc[4][4];
  unsigned pk[4][4][2];                   // packed bf16 intermediate (2 vals/u32)

  // stage 1: hn = h@Whn^T + bhh_n  -> pk
  ZERO_ACC44(acc);
  gate_gemm<256>(acc, Ah, nullptr, whhl + 512*256, nullptr, wc, fr, quad);
  #pragma unroll
  for (int ni=0;ni<4;ni++){
    const float bv = ldext(bhh, bo + 512 + wc + ni*16 + fr, f32);
    #pragma unroll
    for (int mi=0;mi<4;mi++)
      #pragma unroll
      for (int q=0;q<2;q++)
        pk[mi][ni][q] = (unsigned)f2bf(acc[mi][ni][2*q] + bv)
                      | ((unsigned)f2bf(acc[mi][ni][2*q+1] + bv) << 16);
  }

  // stage 2: r = sigm([g|h]@[Wir|Whr]^T + bir + bhr); pk <- r*hn
  ZERO_ACC44(acc);
  gate_gemm<512>(acc, Ag, Ah, wihl, whhl, wc, fr, quad);
  #pragma unroll
  for (int ni=0;ni<4;ni++){
    const int col = wc + ni*16 + fr;
    const float bv = ldext(bih, bo + col, f32) + ldext(bhh, bo + col, f32);
    #pragma unroll
    for (int mi=0;mi<4;mi++)
      #pragma unroll
      for (int q=0;q<2;q++){
        float h0 = bf2f((u16)(pk[mi][ni][q] & 0xFFFFu));
        float h1 = bf2f((u16)(pk[mi][ni][q] >> 16));
        float r0 = sigm(acc[mi][ni][2*q]   + bv);
        float r1 = sigm(acc[mi][ni][2*q+1] + bv);
        pk[mi][ni][q] = (unsigned)f2bf(r0*h0) | ((unsigned)f2bf(r1*h1) << 16);
      }
  }

  // stage 3: n = tanh(g@Win^T + bin + r*hn); pk <- n
  ZERO_ACC44(acc);
  gate_gemm<256>(acc, Ag, nullptr, wihl + 512*256, nullptr, wc, fr, quad);
  #pragma unroll
  for (int ni=0;ni<4;ni++){
    const float bv = ldext(bih, bo + 512 + wc + ni*16 + fr, f32);
    #pragma unroll
    for (int mi=0;mi<4;mi++)
      #pragma unroll
      for (int q=0;q<2;q++){
        float n0 = tanhf(acc[mi][ni][2*q]   + bv + bf2f((u16)(pk[mi][ni][q] & 0xFFFFu)));
        float n1 = tanhf(acc[mi][ni][2*q+1] + bv + bf2f((u16)(pk[mi][ni][q] >> 16)));
        pk[mi][ni][q] = (unsigned)f2bf(n0) | ((unsigned)f2bf(n1) << 16);
      }
  }

  // stage 4: z = sigm([g|h]@[Wiz|Whz]^T + biz + bhz); pk <- (1-z)*n + z*h
  ZERO_ACC44(acc);
  gate_gemm<512>(acc, Ag, Ah, wihl + 256*256, whhl + 256*256, wc, fr, quad);
  #pragma unroll
  for (int ni=0;ni<4;ni++){
    const int col = wc + ni*16 + fr;
    const float bv = ldext(bih, bo + 256 + col, f32) + ldext(bhh, bo + 256 + col, f32);
    #pragma unroll
    for (int mi=0;mi<4;mi++)
      #pragma unroll
      for (int q=0;q<2;q++){
        const int row0 = mi*16 + quad*4 + 2*q;
        const unsigned pv = pk[mi][ni][q];
        float v0, v1;
        {
          const float z = sigm(acc[mi][ni][2*q] + bv);
          const float hval = bf2f(*(const u16*)((const char*)Ah + swzb(row0, col*2)));
          v0 = (1.f - z)*bf2f((u16)(pv & 0xFFFFu)) + z*hval;
        }
        {
          const float z = sigm(acc[mi][ni][2*q+1] + bv);
          const float hval = bf2f(*(const u16*)((const char*)Ah + swzb(row0+1, col*2)));
          v1 = (1.f - z)*bf2f((u16)(pv >> 16)) + z*hval;
        }
        pk[mi][ni][q] = (unsigned)f2bf(v0) | ((unsigned)f2bf(v1) << 16);
      }
  }

  // ---- route hnew through LDS; two-pass LayerNorm (minimal live registers) --
  __syncthreads();                        // all waves done reading Ag/Ah
  #pragma unroll
  for (int ni=0;ni<4;ni++){
    const int col = wc + ni*16 + fr;
    #pragma unroll
    for (int mi=0;mi<4;mi++)
      #pragma unroll
      for (int q=0;q<2;q++){
        const int row0 = mi*16 + quad*4 + 2*q;
        const unsigned pv = pk[mi][ni][q];
        *(u16*)((char*)Ag + swzb(row0,   col*2)) = (u16)(pv & 0xFFFFu);
        *(u16*)((char*)Ag + swzb(row0+1, col*2)) = (u16)(pv >> 16);
      }
  }
  __syncthreads();

  // 4 threads per row, 64 cols each. Pass 1: stats only (2 live floats).
  const int erow = tid >> 2, seg = tid & 3;
  float s1 = 0.f, s2 = 0.f;
  #pragma unroll
  for (int jj=0;jj<16;jj++){
    uint2 w = *(const uint2*)((const char*)Ag + swzb(erow, seg*128 + jj*8));
    float v0 = bf2f((u16)(w.x & 0xFFFFu)), v1 = bf2f((u16)(w.x >> 16));
    float v2 = bf2f((u16)(w.y & 0xFFFFu)), v3 = bf2f((u16)(w.y >> 16));
    s1 += v0 + v1 + v2 + v3;
    s2 += v0*v0 + v1*v1 + v2*v2 + v3*v3;
  }
  s1 += __shfl_xor(s1, 1); s2 += __shfl_xor(s2, 1);
  s1 += __shfl_xor(s1, 2); s2 += __shfl_xor(s2, 2);
  const float mu   = s1 * (1.f/256.f);
  const float var  = s2 * (1.f/256.f) - mu*mu;
  const float rstd = rsqrtf(fmaxf(var, 0.f) + LN_EPS);

  // Pass 2: re-read LDS, normalize, store.
  const size_t rb = (rowBase + erow)*256 + (size_t)seg*64;
  #pragma unroll
  for (int jj=0;jj<16;jj++){
    uint2 w = *(const uint2*)((const char*)Ag + swzb(erow, seg*128 + jj*8));
    const long c0 = seg*64 + jj*4;
    float v0 = (bf2f((u16)(w.x & 0xFFFFu)) - mu)*rstd*ldext(lng, c0+0, f32) + ldext(lnb, c0+0, f32);
    float v1 = (bf2f((u16)(w.x >> 16))     - mu)*rstd*ldext(lng, c0+1, f32) + ldext(lnb, c0+1, f32);
    float v2 = (bf2f((u16)(w.y & 0xFFFFu)) - mu)*rstd*ldext(lng, c0+2, f32) + ldext(lnb, c0+2, f32);
    float v3 = (bf2f((u16)(w.y >> 16))     - mu)*rstd*ldext(lng, c0+3, f32) + ldext(lnb, c0+3, f32);
    *(ushort4*)&hout[rb + jj*4] = make_ushort4(f2bf(v0), f2bf(v1), f2bf(v2), f2bf(v3));
  }
}

// ---- atomic-free segment max over sorted batch: plane -> out slice ----------
__global__ __launch_bounds__(256) void k_segmax(
    const u16* __restrict__ plane, void* __restrict__ out, long slice,
    const int* __restrict__ batch, const int* __restrict__ dflag)
{
  const bool f32 = (*dflag != 0);
  const int g = blockIdx.x*4 + (threadIdx.x >> 6);
  const int lane = threadIdx.x & 63;
  int lo = 0, hi = N_NODES;
  while (lo < hi){ int mid = (lo + hi) >> 1; if (batch[mid] < g) lo = mid + 1; else hi = mid; }
  const int s = lo;
  hi = N_NODES;
  while (lo < hi){ int mid = (lo + hi) >> 1; if (batch[mid] < g + 1) lo = mid + 1; else hi = mid; }
  const int epos = lo;

  const float NINF = __uint_as_float(0xFF800000u);
  float a0=NINF, a1=NINF, a2=NINF, a3=NINF;
  for (int r = s; r < epos; r++){
    ushort4 v = *(const ushort4*)&plane[(size_t)r*256 + lane*4];
    a0 = fmaxf(a0, bf2f(v.x)); a1 = fmaxf(a1, bf2f(v.y));
    a2 = fmaxf(a2, bf2f(v.z)); a3 = fmaxf(a3, bf2f(v.w));
  }
  const long ob = (long)g*1280 + slice + lane*4;
  if (f32){
    float* o = (float*)out + ob;
    o[0]=a0; o[1]=a1; o[2]=a2; o[3]=a3;
  } else {
    *(ushort4*)((u16*)out + ob) = make_ushort4(f2bf(a0), f2bf(a1), f2bf(a2), f2bf(a3));
  }
}

// ---- fused m/e segment max: m = h0*h1*h2, e = h0+h1+h2 (fp32, on the fly) ---
__global__ __launch_bounds__(256) void k_segmax_me(
    const u16* __restrict__ h0, const u16* __restrict__ h1,
    const u16* __restrict__ h2, void* __restrict__ out,
    const int* __restrict__ batch, const int* __restrict__ dflag)
{
  const bool f32 = (*dflag != 0);
  const int g = blockIdx.x*4 + (threadIdx.x >> 6);
  const int lane = threadIdx.x & 63;
  int lo = 0, hi = N_NODES;
  while (lo < hi){ int mid = (lo + hi) >> 1; if (batch[mid] < g) lo = mid + 1; else hi = mid; }
  const int s = lo;
  hi = N_NODES;
  while (lo < hi){ int mid = (lo + hi) >> 1; if (batch[mid] < g + 1) lo = mid + 1; else hi = mid; }
  const int epos = lo;

  const float NINF = __uint_as_float(0xFF800000u);
  float m0=NINF,m1=NINF,m2=NINF,m3=NINF;
  float e0=NINF,e1=NINF,e2=NINF,e3=NINF;
  for (int r = s; r < epos; r++){
    const size_t rb = (size_t)r*256 + lane*4;
    ushort4 a = *(const ushort4*)&h0[rb];
    ushort4 b = *(const ushort4*)&h1[rb];
    ushort4 c = *(const ushort4*)&h2[rb];
    float a0=bf2f(a.x),a1=bf2f(a.y),a2=bf2f(a.z),a3=bf2f(a.w);
    float b0=bf2f(b.x),b1=bf2f(b.y),b2=bf2f(b.z),b3=bf2f(b.w);
    float c0=bf2f(c.x),c1=bf2f(c.y),c2=bf2f(c.z),c3=bf2f(c.w);
    m0=fmaxf(m0,a0*b0*c0); m1=fmaxf(m1,a1*b1*c1);
    m2=fmaxf(m2,a2*b2*c2); m3=fmaxf(m3,a3*b3*c3);
    e0=fmaxf(e0,a0+b0+c0); e1=fmaxf(e1,a1+b1+c1);
    e2=fmaxf(e2,a2+b2+c2); e3=fmaxf(e3,a3+b3+c3);
  }
  const long obm = (long)g*1280 + 768  + lane*4;
  const long obe = (long)g*1280 + 1024 + lane*4;
  if (f32){
    float* o = (float*)out;
    o[obm+0]=m0; o[obm+1]=m1; o[obm+2]=m2; o[obm+3]=m3;
    o[obe+0]=e0; o[obe+1]=e1; o[obe+2]=e2; o[obe+3]=e3;
  } else {
    *(ushort4*)((u16*)out + obm) = make_ushort4(f2bf(m0), f2bf(m1), f2bf(m2), f2bf(m3));
    *(ushort4*)((u16*)out + obe) = make_ushort4(f2bf(e0), f2bf(e1), f2bf(e2), f2bf(e3));
  }
}

// ---- launcher ---------------------------------------------------------------
extern "C" void kernel_launch(void* const* d_in, const int* in_sizes, int n_in,
                              void* d_out, int out_size, void* d_ws, size_t ws_size,
                              hipStream_t stream)
{
  const void* x   = d_in[0];
  const void* l1w = d_in[1];  const void* l1b = d_in[2];
  const void* l2w = d_in[3];  const void* l2b = d_in[4];
  const void* bng = d_in[5];  const void* bnb = d_in[6];
  const void* wih = d_in[7];  const void* whh = d_in[8];
  const void* bih = d_in[9];  const void* bhh = d_in[10];
  const void* lng = d_in[11]; const void* lnb = d_in[12];
  const int* ei    = (const int*)d_in[13];
  const int* batch = (const int*)d_in[14];
  (void)in_sizes; (void)n_in; (void)out_size; (void)ws_size;

  const size_t PL = S_EL * 2;            // bf16 plane bytes (51.25 MB)
  char* p = (char*)d_ws; size_t off = 0;
  auto take = [&](size_t b){ void* q = p + off; off += (b + 255) & ~(size_t)255; return q; };
  u16*      hx   = (u16*)take(PL);       // x (bf16) -> also reused as h2 output
  u16*      hA   = (u16*)take(PL);       // h0
  u16*      hB   = (u16*)take(PL);       // h1
  u16*      G    = (u16*)take(PL);       // agg -> g0 -> g
  float*    bns  = (float*)take(512*4);
  float*    bss  = (float*)take(512*4);  // BN scale/shift interleaved
  int*      dflg = (int*)take(256);
  int*      cnt  = (int*)take((size_t)N_NODES*4);
  int*      bkt  = (int*)take((size_t)N_NODES*CAP*4);   // 12.8 MB
  int*      ovf  = (int*)take((size_t)N_EDGES*4);       // worst-case overflow list
  int*      ovfc = (int*)take(256);
  // bf16 weight copies (all layers): lin1|lin2: 3*64K, wih|whh: 3*192K elems
  u16*      wb1  = (u16*)take((size_t)3*65536*2);
  u16*      wb2  = (u16*)take((size_t)3*65536*2);
  u16*      wbih = (u16*)take((size_t)3*196608*2);
  u16*      wbhh = (u16*)take((size_t)3*196608*2);

  k_detect<<<1, 64, 0, stream>>>((const unsigned*)x, dflg);
  hipMemsetAsync(cnt, 0, (size_t)N_NODES*4, stream);
  hipMemsetAsync(ovfc, 0, 4, stream);
  k_h_init <<<S_EL/8/256, 256, 0, stream>>>(x, hx, dflg);
  k_bucket_build<<<(N_EDGES + 255)/256, 256, 0, stream>>>(ei, cnt, bkt, ovf, ovfc);
  k_wconv<<< 96, 256, 0, stream>>>(l1w, wb1,  dflg);   // 3*65536/8/256
  k_wconv<<< 96, 256, 0, stream>>>(l2w, wb2,  dflg);
  k_wconv<<<288, 256, 0, stream>>>(wih, wbih, dflg);   // 3*196608/8/256
  k_wconv<<<288, 256, 0, stream>>>(whh, wbhh, dflg);

  const u16* hin[3]  = {hx, hA, hB};
  u16*       hout[3] = {hA, hB, hx};     // hx dead after layer-0 staging

  for (int l = 0; l < 3; l++){
    const long bo = (long)l*768;
    hipMemsetAsync(bns, 0, 512*4, stream);
    k_gather<<<(M_PAD*128)/256, 256, 0, stream>>>((const unsigned*)hin[l], cnt, bkt, (unsigned*)G);
    k_ovf_scatter<<<512, 256, 0, stream>>>((const unsigned*)hin[l], ei, ovf, ovfc, (unsigned*)G);

    // fused MLP (lin1+relu+lin2+relu) in-place on G, with fused BN stats
    k_mlp<<<N_TILES*2, 256, 0, stream>>>(G, wb1 + (size_t)l*65536, l1b,
                                         wb2 + (size_t)l*65536, l2b,
                                         (long)l*256, bns, dflg);
    k_bn_fin<<<1, 256, 0, stream>>>(bns, bng, bnb, (long)l*256, bss, dflg);

    // fused GRU + LayerNorm, full grid, h plane rotation
    k_gru<<<N_TILES*2, 256, 0, stream>>>(G, hin[l],
                                         wbih + (size_t)l*196608, wbhh + (size_t)l*196608,
                                         bih, bhh, bo, lng, lnb, bss, hout[l], dflg);

    k_segmax<<<N_GRAPH/4, 256, 0, stream>>>(hout[l], d_out, (long)l*256, batch, dflg);
  }
  // m/e computed on the fly from the three h planes (fp32), then seg-maxed
  k_segmax_me<<<N_GRAPH/4, 256, 0, stream>>>(hA, hB, hx, d_out, batch, dflg);
}

// Round 10
// 1638.969 us; speedup vs baseline: 1.1388x; 1.1388x over previous
//
#include <hip/hip_runtime.h>

// HierarchicalGraphNet: N=100000 nodes, E=320000 edges, D=256, L=3, G=4096.
#define N_NODES 100000
#define N_EDGES 320000
#define N_GRAPH 4096
#define M_PAD   100096                   // N padded to multiple of 128
#define N_TILES 782                      // M_PAD / 128
#define LN_EPS  1e-5f
#define S_EL    ((size_t)M_PAD * 256)    // elements per full M x 256 plane
#define CAP     32                       // in-edge bucket capacity per node

typedef __attribute__((ext_vector_type(8))) short short8;   // 8 x bf16 MFMA operand
typedef __attribute__((ext_vector_type(4))) float f32x4;    // MFMA accumulator
typedef unsigned short u16;

__device__ __forceinline__ float bf2f(u16 u){
  return __uint_as_float(((unsigned)u) << 16);
}
__device__ __forceinline__ u16 f2bf(float f){   // RNE round
  unsigned u = __float_as_uint(f);
  return (u16)((u + 0x7FFFu + ((u >> 16) & 1u)) >> 16);
}
// external float tensor read: fp32 or bf16 per runtime flag
__device__ __forceinline__ float ldext(const void* p, long i, bool f32){
  return f32 ? ((const float*)p)[i] : bf2f(((const u16*)p)[i]);
}
// fast transcendentals (bf16-accurate): v_exp + v_rcp based
__device__ __forceinline__ float fsigm(float x){
  return __builtin_amdgcn_rcpf(1.0f + __expf(-x));
}
__device__ __forceinline__ float ftanh(float x){
  float cx = fminf(fmaxf(x, -15.f), 15.f);        // avoid exp overflow
  return 1.0f - 2.0f*__builtin_amdgcn_rcpf(__expf(2.0f*cx) + 1.0f);
}

// swizzled byte offset inside one A-tile (rows x 256 bf16, row=512B)
// XOR row bits into byte-addr bits [4..6]: breaks row-strided ds_read_b128
// bank conflicts (G4), bijective per 8-row stripe.
__device__ __forceinline__ int swzb(int row, int colByte){
  return (row << 9) + (colByte ^ ((row & 7) << 4));
}

// ---- dtype detector ---------------------------------------------------------
__global__ void k_detect(const unsigned* __restrict__ x32, int* __restrict__ flag){
  unsigned u = x32[threadIdx.x];            // 64 threads
  int ef = (int)((u >> 23) & 0xFFu);
  int ok = (ef >= 64 && ef <= 190) ? 1 : 0;
  #pragma unroll
  for (int o=1; o<64; o<<=1) ok += __shfl_xor(ok, o);
  if (threadIdx.x == 0) *flag = (ok >= 32) ? 1 : 0;
}

// ---- weight pre-conversion to bf16 (runs once, removes f32 from hot loops) --
__global__ void k_wconv(const void* __restrict__ src, u16* __restrict__ dst,
                        const int* __restrict__ dflag){
  const bool f32 = (*dflag != 0);
  size_t base = ((size_t)blockIdx.x*256 + threadIdx.x)*8;
  if (f32){
    const float* s = (const float*)src + base;
    float4 a = *(const float4*)s;
    float4 b = *(const float4*)(s + 4);
    ushort4 lo = make_ushort4(f2bf(a.x),f2bf(a.y),f2bf(a.z),f2bf(a.w));
    ushort4 hi = make_ushort4(f2bf(b.x),f2bf(b.y),f2bf(b.z),f2bf(b.w));
    uint4 v;
    v.x = (unsigned)lo.x | ((unsigned)lo.y<<16);
    v.y = (unsigned)lo.z | ((unsigned)lo.w<<16);
    v.z = (unsigned)hi.x | ((unsigned)hi.y<<16);
    v.w = (unsigned)hi.z | ((unsigned)hi.w<<16);
    *(uint4*)&dst[base] = v;
  } else {
    *(uint4*)&dst[base] = *(const uint4*)((const u16*)src + base);
  }
}

// ---- init kernels -----------------------------------------------------------
__global__ void k_h_init(const void* __restrict__ x, u16* __restrict__ h,
                         const int* __restrict__ dflag){
  const bool f32 = (*dflag != 0);
  int i = blockIdx.x*256 + threadIdx.x;     // 8 elements per thread
  size_t base = (size_t)i*8;
  int n = (int)(base >> 8);
  uint4 v = make_uint4(0,0,0,0);
  if (n < N_NODES){
    if (f32){
      const float* xf = (const float*)x + base;
      float4 a = *(const float4*)xf;
      float4 b = *(const float4*)(xf + 4);
      ushort4 lo = make_ushort4(f2bf(a.x),f2bf(a.y),f2bf(a.z),f2bf(a.w));
      ushort4 hi = make_ushort4(f2bf(b.x),f2bf(b.y),f2bf(b.z),f2bf(b.w));
      v.x = (unsigned)lo.x | ((unsigned)lo.y<<16);
      v.y = (unsigned)lo.z | ((unsigned)lo.w<<16);
      v.z = (unsigned)hi.x | ((unsigned)hi.y<<16);
      v.w = (unsigned)hi.z | ((unsigned)hi.w<<16);
    } else {
      v = *(const uint4*)((const u16*)x + base);
    }
  }
  *(uint4*)&h[base] = v;
}

// ---- inverse-CSR bucket build (edges are static across layers) --------------
__global__ void k_bucket_build(const int* __restrict__ ei, int* __restrict__ cnt,
                               int* __restrict__ bucket, int* __restrict__ ovf,
                               int* __restrict__ ovfcnt){
  int e = blockIdx.x*256 + threadIdx.x;
  if (e >= N_EDGES) return;
  int s = ei[e];
  int d = ei[N_EDGES + e];
  int pos = atomicAdd(&cnt[d], 1);
  if (pos < CAP) bucket[(size_t)d*CAP + pos] = s;
  else { int o = atomicAdd(ovfcnt, 1); ovf[o] = e; }  // o < E always
}

// ---- atomic-free GIN aggregation: G[n] = h[n] + sum_{s->n} h[s] -------------
__global__ __launch_bounds__(256) void k_gather(
    const unsigned* __restrict__ h32, const int* __restrict__ cnt,
    const int* __restrict__ bucket, unsigned* __restrict__ G32)
{
  int gid = blockIdx.x*256 + threadIdx.x;
  int n = gid >> 7;                          // 2 rows per block
  int j = gid & 127;
  unsigned hv = h32[(size_t)n*128 + j];      // pad rows are zero
  float lo = bf2f((u16)(hv & 0xFFFFu));
  float hi = bf2f((u16)(hv >> 16));
  int c = (n < N_NODES) ? min(cnt[n], CAP) : 0;
  const int* bk = &bucket[(size_t)n*CAP];
  for (int k = 0; k < c; k++){
    int s = bk[k];
    unsigned v = h32[(size_t)s*128 + j];
    lo += bf2f((u16)(v & 0xFFFFu));
    hi += bf2f((u16)(v >> 16));
  }
  G32[(size_t)n*128 + j] = (unsigned)f2bf(lo) | ((unsigned)f2bf(hi) << 16);
}

// ---- overflow fallback (normally a no-op) -----------------------------------
__global__ void k_ovf_scatter(const unsigned* __restrict__ h32,
                              const int* __restrict__ ei,
                              const int* __restrict__ ovf,
                              const int* __restrict__ ovfcnt,
                              unsigned* __restrict__ G32){
  const long work = (long)(*ovfcnt) * 128;
  for (long i = (long)blockIdx.x*256 + threadIdx.x; i < work;
       i += (long)gridDim.x*256){
    int e = ovf[i >> 7];
    int j = (int)(i & 127);
    int s = ei[e];
    int d = ei[N_EDGES + e];
    unsigned sv = h32[(size_t)s*128 + j];
    float vlo = bf2f((u16)(sv & 0xFFFFu));
    float vhi = bf2f((u16)(sv >> 16));
    unsigned* addr = &G32[(size_t)d*128 + j];
    unsigned old = *addr;
    while (true){
      unsigned assumed = old;
      u16 nl = f2bf(bf2f((u16)(assumed & 0xFFFFu)) + vlo);
      u16 nh = f2bf(bf2f((u16)(assumed >> 16)) + vhi);
      unsigned nv = (unsigned)nl | ((unsigned)nh << 16);
      old = atomicCAS(addr, assumed, nv);
      if (old == assumed) break;
    }
  }
}

// ---- shared pieces for the fused MFMA kernels (512-thread blocks) -----------
// stage one 64x256 bf16 tile global->LDS, swizzled, fully coalesced
__device__ __forceinline__ void stage_tile64(const u16* __restrict__ g,
                                             u16* __restrict__ tile,
                                             size_t rowBase, int tid){
  #pragma unroll
  for (int j=0;j<4;j++){
    int cid = j*512 + tid;               // 2048 16B chunks
    int r  = cid >> 5;
    int cb = (cid & 31) << 4;            // colByte
    uint4 v = *(const uint4*)((const char*)g + (((rowBase + r) << 9) + cb));
    *(uint4*)((char*)tile + swzb(r, cb)) = v;
  }
}

// same, but applies per-column BatchNorm (ss[2c]=scale, ss[2c+1]=shift)
__device__ __forceinline__ void stage_tile64_bn(const u16* __restrict__ g,
                                                u16* __restrict__ tile,
                                                size_t rowBase, int tid,
                                                const float* __restrict__ ss){
  #pragma unroll
  for (int j=0;j<4;j++){
    int cid = j*512 + tid;
    int r  = cid >> 5;
    int cb = (cid & 31) << 4;            // colByte; bf16 col0 = cb/2
    uint4 v = *(const uint4*)((const char*)g + (((rowBase + r) << 9) + cb));
    unsigned vv[4] = {v.x, v.y, v.z, v.w};
    uint4 o;
    unsigned* op = (unsigned*)&o;
    #pragma unroll
    for (int q=0;q<4;q++){
      float4 s2 = *(const float4*)&ss[cb + q*4];   // sc0,sh0,sc1,sh1
      float x0 = bf2f((u16)(vv[q] & 0xFFFFu))*s2.x + s2.y;
      float x1 = bf2f((u16)(vv[q] >> 16))    *s2.z + s2.w;
      op[q] = (unsigned)f2bf(x0) | ((unsigned)f2bf(x1) << 16);
    }
    *(uint4*)((char*)tile + swzb(r, cb)) = o;
  }
}

// barrier-free K-loop: A from LDS tile(s), B (bf16 weights) from global/L2.
// Wave owns a 64x32 output tile: acc[4][2] fragments of 16x16.
// Explicit depth-1 B prefetch: next kk's weight frags issued before MFMAs,
// hiding the ~200cy L2 latency under the current MFMA group.
template<int KT>
__device__ __forceinline__ void gate_gemm(
    f32x4 (&acc)[4][2], const u16* __restrict__ tA1, const u16* __restrict__ tA2,
    const u16* __restrict__ W1, const u16* __restrict__ W2,
    int wc, int fr, int quad)
{
  constexpr int NH = KT/256;
  const size_t wrow0 = (size_t)(wc + fr)*256 + quad*8;
  const size_t wrow1 = (size_t)(wc + 16 + fr)*256 + quad*8;
  short8 bcur0 = *(const short8*)&W1[wrow0];
  short8 bcur1 = *(const short8*)&W1[wrow1];
  #pragma unroll
  for (int h2=0; h2<NH; h2++){
    const u16* tA = h2 ? tA2 : tA1;
    const u16* Wv = h2 ? W2  : W1;
    #pragma unroll
    for (int kk=0; kk<256; kk+=32){
      short8 af[4];
      #pragma unroll
      for (int mi=0;mi<4;mi++)
        af[mi] = *(const short8*)((const char*)tA + swzb(mi*16 + fr, kk*2 + quad*16));
      short8 bn0 = bcur0, bn1 = bcur1;
      const bool last = (kk == 224) && (h2 == NH-1);
      if (!last){
        const u16* Wn = (kk == 224) ? W2 : Wv;    // NH=2 crossover; never taken at NH=1
        const int   kn = (kk == 224) ? 0  : kk + 32;
        bn0 = *(const short8*)&Wn[wrow0 + kn];
        bn1 = *(const short8*)&Wn[wrow1 + kn];
      }
      #pragma unroll
      for (int mi=0;mi<4;mi++){
        acc[mi][0] = __builtin_amdgcn_mfma_f32_16x16x32_bf16(af[mi], bcur0, acc[mi][0], 0, 0, 0);
        acc[mi][1] = __builtin_amdgcn_mfma_f32_16x16x32_bf16(af[mi], bcur1, acc[mi][1], 0, 0, 0);
      }
      bcur0 = bn0; bcur1 = bn1;
    }
  }
}

#define ZERO_ACC42(a) { f32x4 _z = {0.f,0.f,0.f,0.f}; \
  _Pragma("unroll") for (int _i=0;_i<4;_i++) \
  _Pragma("unroll") for (int _j=0;_j<2;_j++) a[_i][_j] = _z; }

// ---- fused GIN MLP: G = relu(relu(G@W1^T+b1)@W2^T+b2), + BN partial sums ----
// 512 threads, 8 waves (each 64 rows x 32 cols), block = 64 rows x 256 cols.
__global__ __launch_bounds__(512, 2) void k_mlp(
    u16* __restrict__ Gp,
    const u16* __restrict__ w1, const void* __restrict__ b1,
    const u16* __restrict__ w2, const void* __restrict__ b2,
    long bO, float* __restrict__ bns, const int* __restrict__ dflag)
{
  const bool f32 = (*dflag != 0);
  __shared__ u16 Ag[64*256];
  __shared__ u16 At[64*256];
  const int tid = threadIdx.x;
  const size_t rowBase = (size_t)blockIdx.x * 64;
  const int lane = tid & 63, wave = tid >> 6;
  const int wc = wave * 32;
  const int fr = lane & 15, quad = lane >> 4;

  stage_tile64(Gp, Ag, rowBase, tid);
  __syncthreads();

  f32x4 acc[4][2];
  ZERO_ACC42(acc);
  gate_gemm<256>(acc, Ag, nullptr, w1, nullptr, wc, fr, quad);

  // t = relu(acc + b1) -> LDS (swizzled, same layout as Ag)
  #pragma unroll
  for (int ni=0;ni<2;ni++){
    const int col = wc + ni*16 + fr;
    const float bv = ldext(b1, bO + col, f32);
    #pragma unroll
    for (int mi=0;mi<4;mi++)
      #pragma unroll
      for (int r4=0;r4<4;r4++){
        const int row = mi*16 + quad*4 + r4;
        float v = fmaxf(acc[mi][ni][r4] + bv, 0.f);
        *(u16*)((char*)At + swzb(row, col*2)) = f2bf(v);
      }
  }
  __syncthreads();

  ZERO_ACC42(acc);
  gate_gemm<256>(acc, At, nullptr, w2, nullptr, wc, fr, quad);

  // g = relu(acc + b2) -> global, plus per-column BN partial sums
  #pragma unroll
  for (int ni=0;ni<2;ni++){
    const int col = wc + ni*16 + fr;
    const float bv = ldext(b2, bO + col, f32);
    float s1 = 0.f, s2 = 0.f;
    #pragma unroll
    for (int mi=0;mi<4;mi++)
      #pragma unroll
      for (int r4=0;r4<4;r4++){
        const int row = mi*16 + quad*4 + r4;
        const size_t grow = rowBase + row;
        float v = fmaxf(acc[mi][ni][r4] + bv, 0.f);
        Gp[grow*256 + col] = f2bf(v);
        if (grow < N_NODES){ s1 += v; s2 += v*v; }
      }
    s1 += __shfl_xor(s1, 16); s1 += __shfl_xor(s1, 32);   // reduce over quad
    s2 += __shfl_xor(s2, 16); s2 += __shfl_xor(s2, 32);
    if (quad == 0){
      unsafeAtomicAdd(&bns[col],       s1);
      unsafeAtomicAdd(&bns[256 + col], s2);
    }
  }
}

// ---- finalize BN stats -> per-column scale/shift ----------------------------
__global__ void k_bn_fin(const float* __restrict__ sums,
                         const void* __restrict__ gam, const void* __restrict__ bet,
                         long gO, float* __restrict__ ss,
                         const int* __restrict__ dflag){
  const bool f32 = (*dflag != 0);
  int c = threadIdx.x;                     // 256 threads
  float mu  = sums[c] * (1.f/N_NODES);
  float var = sums[256 + c] * (1.f/N_NODES) - mu*mu;
  float sc  = ldext(gam, gO + c, f32) * rsqrtf(fmaxf(var, 0.f) + LN_EPS);
  ss[2*c]     = sc;
  ss[2*c + 1] = ldext(bet, gO + c, f32) - mu*sc;
}

// ---- fused GRU + LayerNorm: hout = LN((1-z)*tanh(gn + r*hn) + z*h) ----------
// 4 single-acc passes (R5 structure, no spill) with 64x32 wave tiles.
__global__ __launch_bounds__(512, 2) void k_gru(
    const u16* __restrict__ Gp, const u16* __restrict__ hp,
    const u16* __restrict__ wihl, const u16* __restrict__ whhl,
    const void* __restrict__ bih, const void* __restrict__ bhh, long bo,
    const void* __restrict__ lng, const void* __restrict__ lnb,
    const float* __restrict__ ss, u16* __restrict__ hout,
    const int* __restrict__ dflag)
{
  const bool f32 = (*dflag != 0);
  __shared__ u16 Ag[64*256];
  __shared__ u16 Ah[64*256];
  const int tid = threadIdx.x;
  const size_t rowBase = (size_t)blockIdx.x * 64;
  const int lane = tid & 63, wave = tid >> 6;
  const int wc = wave * 32;
  const int fr = lane & 15, quad = lane >> 4;

  stage_tile64_bn(Gp, Ag, rowBase, tid, ss);   // Ag = BN(G)  (g input)
  stage_tile64(hp, Ah, rowBase, tid);
  __syncthreads();

  f32x4 acc[4][2];
  unsigned pk[4][2][2];                   // packed bf16 intermediate (2 vals/u32)

  // stage 1: hn = h@Whn^T + bhh_n  -> pk
  ZERO_ACC42(acc);
  gate_gemm<256>(acc, Ah, nullptr, whhl + 512*256, nullptr, wc, fr, quad);
  #pragma unroll
  for (int ni=0;ni<2;ni++){
    const float bv = ldext(bhh, bo + 512 + wc + ni*16 + fr, f32);
    #pragma unroll
    for (int mi=0;mi<4;mi++)
      #pragma unroll
      for (int q=0;q<2;q++)
        pk[mi][ni][q] = (unsigned)f2bf(acc[mi][ni][2*q] + bv)
                      | ((unsigned)f2bf(acc[mi][ni][2*q+1] + bv) << 16);
  }

  // stage 2: r = sigm([g|h]@[Wir|Whr]^T + bir + bhr); pk <- r*hn
  ZERO_ACC42(acc);
  gate_gemm<512>(acc, Ag, Ah, wihl, whhl, wc, fr, quad);
  #pragma unroll
  for (int ni=0;ni<2;ni++){
    const int col = wc + ni*16 + fr;
    const float bv = ldext(bih, bo + col, f32) + ldext(bhh, bo + col, f32);
    #pragma unroll
    for (int mi=0;mi<4;mi++)
      #pragma unroll
      for (int q=0;q<2;q++){
        float h0 = bf2f((u16)(pk[mi][ni][q] & 0xFFFFu));
        float h1 = bf2f((u16)(pk[mi][ni][q] >> 16));
        float r0 = fsigm(acc[mi][ni][2*q]   + bv);
        float r1 = fsigm(acc[mi][ni][2*q+1] + bv);
        pk[mi][ni][q] = (unsigned)f2bf(r0*h0) | ((unsigned)f2bf(r1*h1) << 16);
      }
  }

  // stage 3: n = tanh(g@Win^T + bin + r*hn); pk <- n
  ZERO_ACC42(acc);
  gate_gemm<256>(acc, Ag, nullptr, wihl + 512*256, nullptr, wc, fr, quad);
  #pragma unroll
  for (int ni=0;ni<2;ni++){
    const float bv = ldext(bih, bo + 512 + wc + ni*16 + fr, f32);
    #pragma unroll
    for (int mi=0;mi<4;mi++)
      #pragma unroll
      for (int q=0;q<2;q++){
        float n0 = ftanh(acc[mi][ni][2*q]   + bv + bf2f((u16)(pk[mi][ni][q] & 0xFFFFu)));
        float n1 = ftanh(acc[mi][ni][2*q+1] + bv + bf2f((u16)(pk[mi][ni][q] >> 16)));
        pk[mi][ni][q] = (unsigned)f2bf(n0) | ((unsigned)f2bf(n1) << 16);
      }
  }

  // stage 4: z = sigm([g|h]@[Wiz|Whz]^T + biz + bhz); pk <- (1-z)*n + z*h
  ZERO_ACC42(acc);
  gate_gemm<512>(acc, Ag, Ah, wihl + 256*256, whhl + 256*256, wc, fr, quad);
  #pragma unroll
  for (int ni=0;ni<2;ni++){
    const int col = wc + ni*16 + fr;
    const float bv = ldext(bih, bo + 256 + col, f32) + ldext(bhh, bo + 256 + col, f32);
    #pragma unroll
    for (int mi=0;mi<4;mi++)
      #pragma unroll
      for (int q=0;q<2;q++){
        const int row0 = mi*16 + quad*4 + 2*q;
        const unsigned pv = pk[mi][ni][q];
        float v0, v1;
        {
          const float z = fsigm(acc[mi][ni][2*q] + bv);
          const float hval = bf2f(*(const u16*)((const char*)Ah + swzb(row0, col*2)));
          v0 = (1.f - z)*bf2f((u16)(pv & 0xFFFFu)) + z*hval;
        }
        {
          const float z = fsigm(acc[mi][ni][2*q+1] + bv);
          const float hval = bf2f(*(const u16*)((const char*)Ah + swzb(row0+1, col*2)));
          v1 = (1.f - z)*bf2f((u16)(pv >> 16)) + z*hval;
        }
        pk[mi][ni][q] = (unsigned)f2bf(v0) | ((unsigned)f2bf(v1) << 16);
      }
  }

  // ---- route hnew through LDS; two-pass LayerNorm (minimal live registers) --
  __syncthreads();                        // all waves done reading Ag/Ah
  #pragma unroll
  for (int ni=0;ni<2;ni++){
    const int col = wc + ni*16 + fr;
    #pragma unroll
    for (int mi=0;mi<4;mi++)
      #pragma unroll
      for (int q=0;q<2;q++){
        const int row0 = mi*16 + quad*4 + 2*q;
        const unsigned pv = pk[mi][ni][q];
        *(u16*)((char*)Ag + swzb(row0,   col*2)) = (u16)(pv & 0xFFFFu);
        *(u16*)((char*)Ag + swzb(row0+1, col*2)) = (u16)(pv >> 16);
      }
  }
  __syncthreads();

  // 8 threads per row, 32 cols each. Pass 1: stats only (2 live floats).
  const int erow = tid >> 3, seg = tid & 7;
  float s1 = 0.f, s2 = 0.f;
  #pragma unroll
  for (int jj=0;jj<8;jj++){
    uint2 w = *(const uint2*)((const char*)Ag + swzb(erow, seg*64 + jj*8));
    float v0 = bf2f((u16)(w.x & 0xFFFFu)), v1 = bf2f((u16)(w.x >> 16));
    float v2 = bf2f((u16)(w.y & 0xFFFFu)), v3 = bf2f((u16)(w.y >> 16));
    s1 += v0 + v1 + v2 + v3;
    s2 += v0*v0 + v1*v1 + v2*v2 + v3*v3;
  }
  s1 += __shfl_xor(s1, 1); s2 += __shfl_xor(s2, 1);
  s1 += __shfl_xor(s1, 2); s2 += __shfl_xor(s2, 2);
  s1 += __shfl_xor(s1, 4); s2 += __shfl_xor(s2, 4);
  const float mu   = s1 * (1.f/256.f);
  const float var  = s2 * (1.f/256.f) - mu*mu;
  const float rstd = rsqrtf(fmaxf(var, 0.f) + LN_EPS);

  // Pass 2: re-read LDS, normalize, store.
  const size_t rb = (rowBase + erow)*256 + (size_t)seg*32;
  #pragma unroll
  for (int jj=0;jj<8;jj++){
    uint2 w = *(const uint2*)((const char*)Ag + swzb(erow, seg*64 + jj*8));
    const long c0 = seg*32 + jj*4;
    float v0 = (bf2f((u16)(w.x & 0xFFFFu)) - mu)*rstd*ldext(lng, c0+0, f32) + ldext(lnb, c0+0, f32);
    float v1 = (bf2f((u16)(w.x >> 16))     - mu)*rstd*ldext(lng, c0+1, f32) + ldext(lnb, c0+1, f32);
    float v2 = (bf2f((u16)(w.y & 0xFFFFu)) - mu)*rstd*ldext(lng, c0+2, f32) + ldext(lnb, c0+2, f32);
    float v3 = (bf2f((u16)(w.y >> 16))     - mu)*rstd*ldext(lng, c0+3, f32) + ldext(lnb, c0+3, f32);
    *(ushort4*)&hout[rb + jj*4] = make_ushort4(f2bf(v0), f2bf(v1), f2bf(v2), f2bf(v3));
  }
}

// ---- atomic-free segment max over sorted batch: plane -> out slice ----------
__global__ __launch_bounds__(256) void k_segmax(
    const u16* __restrict__ plane, void* __restrict__ out, long slice,
    const int* __restrict__ batch, const int* __restrict__ dflag)
{
  const bool f32 = (*dflag != 0);
  const int g = blockIdx.x*4 + (threadIdx.x >> 6);
  const int lane = threadIdx.x & 63;
  int lo = 0, hi = N_NODES;
  while (lo < hi){ int mid = (lo + hi) >> 1; if (batch[mid] < g) lo = mid + 1; else hi = mid; }
  const int s = lo;
  hi = N_NODES;
  while (lo < hi){ int mid = (lo + hi) >> 1; if (batch[mid] < g + 1) lo = mid + 1; else hi = mid; }
  const int epos = lo;

  const float NINF = __uint_as_float(0xFF800000u);
  float a0=NINF, a1=NINF, a2=NINF, a3=NINF;
  for (int r = s; r < epos; r++){
    ushort4 v = *(const ushort4*)&plane[(size_t)r*256 + lane*4];
    a0 = fmaxf(a0, bf2f(v.x)); a1 = fmaxf(a1, bf2f(v.y));
    a2 = fmaxf(a2, bf2f(v.z)); a3 = fmaxf(a3, bf2f(v.w));
  }
  const long ob = (long)g*1280 + slice + lane*4;
  if (f32){
    float* o = (float*)out + ob;
    o[0]=a0; o[1]=a1; o[2]=a2; o[3]=a3;
  } else {
    *(ushort4*)((u16*)out + ob) = make_ushort4(f2bf(a0), f2bf(a1), f2bf(a2), f2bf(a3));
  }
}

// ---- fused m/e segment max: m = h0*h1*h2, e = h0+h1+h2 (fp32, on the fly) ---
__global__ __launch_bounds__(256) void k_segmax_me(
    const u16* __restrict__ h0, const u16* __restrict__ h1,
    const u16* __restrict__ h2, void* __restrict__ out,
    const int* __restrict__ batch, const int* __restrict__ dflag)
{
  const bool f32 = (*dflag != 0);
  const int g = blockIdx.x*4 + (threadIdx.x >> 6);
  const int lane = threadIdx.x & 63;
  int lo = 0, hi = N_NODES;
  while (lo < hi){ int mid = (lo + hi) >> 1; if (batch[mid] < g) lo = mid + 1; else hi = mid; }
  const int s = lo;
  hi = N_NODES;
  while (lo < hi){ int mid = (lo + hi) >> 1; if (batch[mid] < g + 1) lo = mid + 1; else hi = mid; }
  const int epos = lo;

  const float NINF = __uint_as_float(0xFF800000u);
  float m0=NINF,m1=NINF,m2=NINF,m3=NINF;
  float e0=NINF,e1=NINF,e2=NINF,e3=NINF;
  for (int r = s; r < epos; r++){
    const size_t rb = (size_t)r*256 + lane*4;
    ushort4 a = *(const ushort4*)&h0[rb];
    ushort4 b = *(const ushort4*)&h1[rb];
    ushort4 c = *(const ushort4*)&h2[rb];
    float a0=bf2f(a.x),a1=bf2f(a.y),a2=bf2f(a.z),a3=bf2f(a.w);
    float b0=bf2f(b.x),b1=bf2f(b.y),b2=bf2f(b.z),b3=bf2f(b.w);
    float c0=bf2f(c.x),c1=bf2f(c.y),c2=bf2f(c.z),c3=bf2f(c.w);
    m0=fmaxf(m0,a0*b0*c0); m1=fmaxf(m1,a1*b1*c1);
    m2=fmaxf(m2,a2*b2*c2); m3=fmaxf(m3,a3*b3*c3);
    e0=fmaxf(e0,a0+b0+c0); e1=fmaxf(e1,a1+b1+c1);
    e2=fmaxf(e2,a2+b2+c2); e3=fmaxf(e3,a3+b3+c3);
  }
  const long obm = (long)g*1280 + 768  + lane*4;
  const long obe = (long)g*1280 + 1024 + lane*4;
  if (f32){
    float* o = (float*)out;
    o[obm+0]=m0; o[obm+1]=m1; o[obm+2]=m2; o[obm+3]=m3;
    o[obe+0]=e0; o[obe+1]=e1; o[obe+2]=e2; o[obe+3]=e3;
  } else {
    *(ushort4*)((u16*)out + obm) = make_ushort4(f2bf(m0), f2bf(m1), f2bf(m2), f2bf(m3));
    *(ushort4*)((u16*)out + obe) = make_ushort4(f2bf(e0), f2bf(e1), f2bf(e2), f2bf(e3));
  }
}

// ---- launcher ---------------------------------------------------------------
extern "C" void kernel_launch(void* const* d_in, const int* in_sizes, int n_in,
                              void* d_out, int out_size, void* d_ws, size_t ws_size,
                              hipStream_t stream)
{
  const void* x   = d_in[0];
  const void* l1w = d_in[1];  const void* l1b = d_in[2];
  const void* l2w = d_in[3];  const void* l2b = d_in[4];
  const void* bng = d_in[5];  const void* bnb = d_in[6];
  const void* wih = d_in[7];  const void* whh = d_in[8];
  const void* bih = d_in[9];  const void* bhh = d_in[10];
  const void* lng = d_in[11]; const void* lnb = d_in[12];
  const int* ei    = (const int*)d_in[13];
  const int* batch = (const int*)d_in[14];
  (void)in_sizes; (void)n_in; (void)out_size; (void)ws_size;

  const size_t PL = S_EL * 2;            // bf16 plane bytes (51.25 MB)
  char* p = (char*)d_ws; size_t off = 0;
  auto take = [&](size_t b){ void* q = p + off; off += (b + 255) & ~(size_t)255; return q; };
  u16*      hx   = (u16*)take(PL);       // x (bf16) -> also reused as h2 output
  u16*      hA   = (u16*)take(PL);       // h0
  u16*      hB   = (u16*)take(PL);       // h1
  u16*      G    = (u16*)take(PL);       // agg -> g0 -> g
  float*    bns  = (float*)take(512*4);
  float*    bss  = (float*)take(512*4);  // BN scale/shift interleaved
  int*      dflg = (int*)take(256);
  int*      cnt  = (int*)take((size_t)N_NODES*4);
  int*      bkt  = (int*)take((size_t)N_NODES*CAP*4);   // 12.8 MB
  int*      ovf  = (int*)take((size_t)N_EDGES*4);       // worst-case overflow list
  int*      ovfc = (int*)take(256);
  // bf16 weight copies (all layers): lin1|lin2: 3*64K, wih|whh: 3*192K elems
  u16*      wb1  = (u16*)take((size_t)3*65536*2);
  u16*      wb2  = (u16*)take((size_t)3*65536*2);
  u16*      wbih = (u16*)take((size_t)3*196608*2);
  u16*      wbhh = (u16*)take((size_t)3*196608*2);

  k_detect<<<1, 64, 0, stream>>>((const unsigned*)x, dflg);
  hipMemsetAsync(cnt, 0, (size_t)N_NODES*4, stream);
  hipMemsetAsync(ovfc, 0, 4, stream);
  k_h_init <<<S_EL/8/256, 256, 0, stream>>>(x, hx, dflg);
  k_bucket_build<<<(N_EDGES + 255)/256, 256, 0, stream>>>(ei, cnt, bkt, ovf, ovfc);
  k_wconv<<< 96, 256, 0, stream>>>(l1w, wb1,  dflg);   // 3*65536/8/256
  k_wconv<<< 96, 256, 0, stream>>>(l2w, wb2,  dflg);
  k_wconv<<<288, 256, 0, stream>>>(wih, wbih, dflg);   // 3*196608/8/256
  k_wconv<<<288, 256, 0, stream>>>(whh, wbhh, dflg);

  const u16* hin[3]  = {hx, hA, hB};
  u16*       hout[3] = {hA, hB, hx};     // hx dead after layer-0 staging

  for (int l = 0; l < 3; l++){
    const long bo = (long)l*768;
    hipMemsetAsync(bns, 0, 512*4, stream);
    k_gather<<<(M_PAD*128)/256, 256, 0, stream>>>((const unsigned*)hin[l], cnt, bkt, (unsigned*)G);
    k_ovf_scatter<<<512, 256, 0, stream>>>((const unsigned*)hin[l], ei, ovf, ovfc, (unsigned*)G);

    // fused MLP (lin1+relu+lin2+relu) in-place on G, with fused BN stats
    k_mlp<<<N_TILES*2, 512, 0, stream>>>(G, wb1 + (size_t)l*65536, l1b,
                                         wb2 + (size_t)l*65536, l2b,
                                         (long)l*256, bns, dflg);
    k_bn_fin<<<1, 256, 0, stream>>>(bns, bng, bnb, (long)l*256, bss, dflg);

    // fused GRU + LayerNorm, full grid, h plane rotation
    k_gru<<<N_TILES*2, 512, 0, stream>>>(G, hin[l],
                                         wbih + (size_t)l*196608, wbhh + (size_t)l*196608,
                                         bih, bhh, bo, lng, lnb, bss, hout[l], dflg);

    k_segmax<<<N_GRAPH/4, 256, 0, stream>>>(hout[l], d_out, (long)l*256, batch, dflg);
  }
  // m/e computed on the fly from the three h planes (fp32), then seg-maxed
  k_segmax_me<<<N_GRAPH/4, 256, 0, stream>>>(hA, hB, hx, d_out, batch, dflg);
}

// Round 11
// 1567.086 us; speedup vs baseline: 1.1910x; 1.0459x over previous
//
#include <hip/hip_runtime.h>

// HierarchicalGraphNet: N=100000 nodes, E=320000 edges, D=256, L=3, G=4096.
#define N_NODES 100000
#define N_EDGES 320000
#define N_GRAPH 4096
#define M_PAD   100096                   // N padded to multiple of 128
#define N_TILES 782                      // M_PAD / 128
#define LN_EPS  1e-5f
#define S_EL    ((size_t)M_PAD * 256)    // elements per full M x 256 plane
#define CAP     32                       // in-edge bucket capacity per node

typedef __attribute__((ext_vector_type(8))) short short8;   // 8 x bf16 MFMA operand
typedef __attribute__((ext_vector_type(4))) float f32x4;    // MFMA accumulator
typedef unsigned short u16;

__device__ __forceinline__ float bf2f(u16 u){
  return __uint_as_float(((unsigned)u) << 16);
}
__device__ __forceinline__ u16 f2bf(float f){   // RNE round
  unsigned u = __float_as_uint(f);
  return (u16)((u + 0x7FFFu + ((u >> 16) & 1u)) >> 16);
}
// external float tensor read: fp32 or bf16 per runtime flag
__device__ __forceinline__ float ldext(const void* p, long i, bool f32){
  return f32 ? ((const float*)p)[i] : bf2f(((const u16*)p)[i]);
}
// fast transcendentals (bf16-accurate): v_exp + v_rcp based
__device__ __forceinline__ float fsigm(float x){
  return __builtin_amdgcn_rcpf(1.0f + __expf(-x));
}
__device__ __forceinline__ float ftanh(float x){
  float cx = fminf(fmaxf(x, -15.f), 15.f);        // avoid exp overflow
  return 1.0f - 2.0f*__builtin_amdgcn_rcpf(__expf(2.0f*cx) + 1.0f);
}

// swizzled byte offset inside one A-tile (rows x 256 bf16, row=512B)
// XOR row bits into byte-addr bits [4..6]: breaks row-strided ds_read_b128
// bank conflicts (G4), bijective per 8-row stripe.
__device__ __forceinline__ int swzb(int row, int colByte){
  return (row << 9) + (colByte ^ ((row & 7) << 4));
}

// ---- dtype detector ---------------------------------------------------------
__global__ void k_detect(const unsigned* __restrict__ x32, int* __restrict__ flag){
  unsigned u = x32[threadIdx.x];            // 64 threads
  int ef = (int)((u >> 23) & 0xFFu);
  int ok = (ef >= 64 && ef <= 190) ? 1 : 0;
  #pragma unroll
  for (int o=1; o<64; o<<=1) ok += __shfl_xor(ok, o);
  if (threadIdx.x == 0) *flag = (ok >= 32) ? 1 : 0;
}

// ---- weight pre-conversion to bf16 (runs once, removes f32 from hot loops) --
__global__ void k_wconv(const void* __restrict__ src, u16* __restrict__ dst,
                        const int* __restrict__ dflag){
  const bool f32 = (*dflag != 0);
  size_t base = ((size_t)blockIdx.x*256 + threadIdx.x)*8;
  if (f32){
    const float* s = (const float*)src + base;
    float4 a = *(const float4*)s;
    float4 b = *(const float4*)(s + 4);
    ushort4 lo = make_ushort4(f2bf(a.x),f2bf(a.y),f2bf(a.z),f2bf(a.w));
    ushort4 hi = make_ushort4(f2bf(b.x),f2bf(b.y),f2bf(b.z),f2bf(b.w));
    uint4 v;
    v.x = (unsigned)lo.x | ((unsigned)lo.y<<16);
    v.y = (unsigned)lo.z | ((unsigned)lo.w<<16);
    v.z = (unsigned)hi.x | ((unsigned)hi.y<<16);
    v.w = (unsigned)hi.z | ((unsigned)hi.w<<16);
    *(uint4*)&dst[base] = v;
  } else {
    *(uint4*)&dst[base] = *(const uint4*)((const u16*)src + base);
  }
}

// ---- init kernels -----------------------------------------------------------
__global__ void k_h_init(const void* __restrict__ x, u16* __restrict__ h,
                         const int* __restrict__ dflag){
  const bool f32 = (*dflag != 0);
  int i = blockIdx.x*256 + threadIdx.x;     // 8 elements per thread
  size_t base = (size_t)i*8;
  int n = (int)(base >> 8);
  uint4 v = make_uint4(0,0,0,0);
  if (n < N_NODES){
    if (f32){
      const float* xf = (const float*)x + base;
      float4 a = *(const float4*)xf;
      float4 b = *(const float4*)(xf + 4);
      ushort4 lo = make_ushort4(f2bf(a.x),f2bf(a.y),f2bf(a.z),f2bf(a.w));
      ushort4 hi = make_ushort4(f2bf(b.x),f2bf(b.y),f2bf(b.z),f2bf(b.w));
      v.x = (unsigned)lo.x | ((unsigned)lo.y<<16);
      v.y = (unsigned)lo.z | ((unsigned)lo.w<<16);
      v.z = (unsigned)hi.x | ((unsigned)hi.y<<16);
      v.w = (unsigned)hi.z | ((unsigned)hi.w<<16);
    } else {
      v = *(const uint4*)((const u16*)x + base);
    }
  }
  *(uint4*)&h[base] = v;
}

// ---- inverse-CSR bucket build (edges are static across layers) --------------
__global__ void k_bucket_build(const int* __restrict__ ei, int* __restrict__ cnt,
                               int* __restrict__ bucket, int* __restrict__ ovf,
                               int* __restrict__ ovfcnt){
  int e = blockIdx.x*256 + threadIdx.x;
  if (e >= N_EDGES) return;
  int s = ei[e];
  int d = ei[N_EDGES + e];
  int pos = atomicAdd(&cnt[d], 1);
  if (pos < CAP) bucket[(size_t)d*CAP + pos] = s;
  else { int o = atomicAdd(ovfcnt, 1); ovf[o] = e; }  // o < E always
}

// ---- atomic-free GIN aggregation: G[n] = h[n] + sum_{s->n} h[s] -------------
__global__ __launch_bounds__(256) void k_gather(
    const unsigned* __restrict__ h32, const int* __restrict__ cnt,
    const int* __restrict__ bucket, unsigned* __restrict__ G32)
{
  int gid = blockIdx.x*256 + threadIdx.x;
  int n = gid >> 7;                          // 2 rows per block
  int j = gid & 127;
  unsigned hv = h32[(size_t)n*128 + j];      // pad rows are zero
  float lo = bf2f((u16)(hv & 0xFFFFu));
  float hi = bf2f((u16)(hv >> 16));
  int c = (n < N_NODES) ? min(cnt[n], CAP) : 0;
  const int* bk = &bucket[(size_t)n*CAP];
  for (int k = 0; k < c; k++){
    int s = bk[k];
    unsigned v = h32[(size_t)s*128 + j];
    lo += bf2f((u16)(v & 0xFFFFu));
    hi += bf2f((u16)(v >> 16));
  }
  G32[(size_t)n*128 + j] = (unsigned)f2bf(lo) | ((unsigned)f2bf(hi) << 16);
}

// ---- overflow fallback (normally a no-op) -----------------------------------
__global__ void k_ovf_scatter(const unsigned* __restrict__ h32,
                              const int* __restrict__ ei,
                              const int* __restrict__ ovf,
                              const int* __restrict__ ovfcnt,
                              unsigned* __restrict__ G32){
  const long work = (long)(*ovfcnt) * 128;
  for (long i = (long)blockIdx.x*256 + threadIdx.x; i < work;
       i += (long)gridDim.x*256){
    int e = ovf[i >> 7];
    int j = (int)(i & 127);
    int s = ei[e];
    int d = ei[N_EDGES + e];
    unsigned sv = h32[(size_t)s*128 + j];
    float vlo = bf2f((u16)(sv & 0xFFFFu));
    float vhi = bf2f((u16)(sv >> 16));
    unsigned* addr = &G32[(size_t)d*128 + j];
    unsigned old = *addr;
    while (true){
      unsigned assumed = old;
      u16 nl = f2bf(bf2f((u16)(assumed & 0xFFFFu)) + vlo);
      u16 nh = f2bf(bf2f((u16)(assumed >> 16)) + vhi);
      unsigned nv = (unsigned)nl | ((unsigned)nh << 16);
      old = atomicCAS(addr, assumed, nv);
      if (old == assumed) break;
    }
  }
}

// ---- shared pieces for the fused MFMA kernels (512-thread blocks) -----------
// stage one 64x256 bf16 tile global->LDS, swizzled, fully coalesced
__device__ __forceinline__ void stage_tile64(const u16* __restrict__ g,
                                             u16* __restrict__ tile,
                                             size_t rowBase, int tid){
  #pragma unroll
  for (int j=0;j<4;j++){
    int cid = j*512 + tid;               // 2048 16B chunks
    int r  = cid >> 5;
    int cb = (cid & 31) << 4;            // colByte
    uint4 v = *(const uint4*)((const char*)g + (((rowBase + r) << 9) + cb));
    *(uint4*)((char*)tile + swzb(r, cb)) = v;
  }
}

// same, but applies per-column BatchNorm (ss[2c]=scale, ss[2c+1]=shift)
__device__ __forceinline__ void stage_tile64_bn(const u16* __restrict__ g,
                                                u16* __restrict__ tile,
                                                size_t rowBase, int tid,
                                                const float* __restrict__ ss){
  #pragma unroll
  for (int j=0;j<4;j++){
    int cid = j*512 + tid;
    int r  = cid >> 5;
    int cb = (cid & 31) << 4;            // colByte; bf16 col0 = cb/2
    uint4 v = *(const uint4*)((const char*)g + (((rowBase + r) << 9) + cb));
    unsigned vv[4] = {v.x, v.y, v.z, v.w};
    uint4 o;
    unsigned* op = (unsigned*)&o;
    #pragma unroll
    for (int q=0;q<4;q++){
      float4 s2 = *(const float4*)&ss[cb + q*4];   // sc0,sh0,sc1,sh1
      float x0 = bf2f((u16)(vv[q] & 0xFFFFu))*s2.x + s2.y;
      float x1 = bf2f((u16)(vv[q] >> 16))    *s2.z + s2.w;
      op[q] = (unsigned)f2bf(x0) | ((unsigned)f2bf(x1) << 16);
    }
    *(uint4*)((char*)tile + swzb(r, cb)) = o;
  }
}

// barrier-free K-loop: A from LDS tile(s), B (bf16 weights) from global/L2.
// Wave owns a 64x32 output tile: acc[4][2] fragments of 16x16.
// Depth-1 prefetch of BOTH operands: kk+1's A ds_reads and B global loads are
// issued before kk's MFMA group, hiding ~120cy LDS and ~200cy L2 latency.
template<int KT>
__device__ __forceinline__ void gate_gemm(
    f32x4 (&acc)[4][2], const u16* __restrict__ tA1, const u16* __restrict__ tA2,
    const u16* __restrict__ W1, const u16* __restrict__ W2,
    int wc, int fr, int quad)
{
  constexpr int NH = KT/256;
  const size_t wrow0 = (size_t)(wc + fr)*256 + quad*8;
  const size_t wrow1 = (size_t)(wc + 16 + fr)*256 + quad*8;
  short8 acur[4];
  #pragma unroll
  for (int mi=0;mi<4;mi++)
    acur[mi] = *(const short8*)((const char*)tA1 + swzb(mi*16 + fr, quad*16));
  short8 bcur0 = *(const short8*)&W1[wrow0];
  short8 bcur1 = *(const short8*)&W1[wrow1];
  #pragma unroll
  for (int h2=0; h2<NH; h2++){
    #pragma unroll
    for (int kk=0; kk<256; kk+=32){
      const bool last = (kk == 224) && (h2 == NH-1);
      short8 an[4], bn0, bn1;
      if (!last){
        const u16* tAn = (kk == 224) ? tA2 : (h2 ? tA2 : tA1);
        const u16* Wn  = (kk == 224) ? W2  : (h2 ? W2  : W1);
        const int   kn = (kk == 224) ? 0  : kk + 32;
        #pragma unroll
        for (int mi=0;mi<4;mi++)
          an[mi] = *(const short8*)((const char*)tAn + swzb(mi*16 + fr, kn*2 + quad*16));
        bn0 = *(const short8*)&Wn[wrow0 + kn];
        bn1 = *(const short8*)&Wn[wrow1 + kn];
      }
      #pragma unroll
      for (int mi=0;mi<4;mi++){
        acc[mi][0] = __builtin_amdgcn_mfma_f32_16x16x32_bf16(acur[mi], bcur0, acc[mi][0], 0, 0, 0);
        acc[mi][1] = __builtin_amdgcn_mfma_f32_16x16x32_bf16(acur[mi], bcur1, acc[mi][1], 0, 0, 0);
      }
      if (!last){
        #pragma unroll
        for (int mi=0;mi<4;mi++) acur[mi] = an[mi];
        bcur0 = bn0; bcur1 = bn1;
      }
    }
  }
}

#define ZERO_ACC42(a) { f32x4 _z = {0.f,0.f,0.f,0.f}; \
  _Pragma("unroll") for (int _i=0;_i<4;_i++) \
  _Pragma("unroll") for (int _j=0;_j<2;_j++) a[_i][_j] = _z; }

// ---- fused GIN MLP: G = relu(relu(G@W1^T+b1)@W2^T+b2), + BN partial sums ----
// 512 threads, 8 waves (each 64 rows x 32 cols), block = 64 rows x 256 cols.
__global__ __launch_bounds__(512, 2) void k_mlp(
    u16* __restrict__ Gp,
    const u16* __restrict__ w1, const void* __restrict__ b1,
    const u16* __restrict__ w2, const void* __restrict__ b2,
    long bO, float* __restrict__ bns, const int* __restrict__ dflag)
{
  const bool f32 = (*dflag != 0);
  __shared__ u16 Ag[64*256];
  __shared__ u16 At[64*256];
  const int tid = threadIdx.x;
  const size_t rowBase = (size_t)blockIdx.x * 64;
  const int lane = tid & 63, wave = tid >> 6;
  const int wc = wave * 32;
  const int fr = lane & 15, quad = lane >> 4;

  stage_tile64(Gp, Ag, rowBase, tid);
  __syncthreads();

  f32x4 acc[4][2];
  ZERO_ACC42(acc);
  gate_gemm<256>(acc, Ag, nullptr, w1, nullptr, wc, fr, quad);

  // t = relu(acc + b1) -> LDS (swizzled, same layout as Ag)
  #pragma unroll
  for (int ni=0;ni<2;ni++){
    const int col = wc + ni*16 + fr;
    const float bv = ldext(b1, bO + col, f32);
    #pragma unroll
    for (int mi=0;mi<4;mi++)
      #pragma unroll
      for (int r4=0;r4<4;r4++){
        const int row = mi*16 + quad*4 + r4;
        float v = fmaxf(acc[mi][ni][r4] + bv, 0.f);
        *(u16*)((char*)At + swzb(row, col*2)) = f2bf(v);
      }
  }
  __syncthreads();

  ZERO_ACC42(acc);
  gate_gemm<256>(acc, At, nullptr, w2, nullptr, wc, fr, quad);

  // g = relu(acc + b2) -> global, plus per-column BN partial sums
  #pragma unroll
  for (int ni=0;ni<2;ni++){
    const int col = wc + ni*16 + fr;
    const float bv = ldext(b2, bO + col, f32);
    float s1 = 0.f, s2 = 0.f;
    #pragma unroll
    for (int mi=0;mi<4;mi++)
      #pragma unroll
      for (int r4=0;r4<4;r4++){
        const int row = mi*16 + quad*4 + r4;
        const size_t grow = rowBase + row;
        float v = fmaxf(acc[mi][ni][r4] + bv, 0.f);
        Gp[grow*256 + col] = f2bf(v);
        if (grow < N_NODES){ s1 += v; s2 += v*v; }
      }
    s1 += __shfl_xor(s1, 16); s1 += __shfl_xor(s1, 32);   // reduce over quad
    s2 += __shfl_xor(s2, 16); s2 += __shfl_xor(s2, 32);
    if (quad == 0){
      unsafeAtomicAdd(&bns[col],       s1);
      unsafeAtomicAdd(&bns[256 + col], s2);
    }
  }
}

// ---- finalize BN stats -> per-column scale/shift ----------------------------
__global__ void k_bn_fin(const float* __restrict__ sums,
                         const void* __restrict__ gam, const void* __restrict__ bet,
                         long gO, float* __restrict__ ss,
                         const int* __restrict__ dflag){
  const bool f32 = (*dflag != 0);
  int c = threadIdx.x;                     // 256 threads
  float mu  = sums[c] * (1.f/N_NODES);
  float var = sums[256 + c] * (1.f/N_NODES) - mu*mu;
  float sc  = ldext(gam, gO + c, f32) * rsqrtf(fmaxf(var, 0.f) + LN_EPS);
  ss[2*c]     = sc;
  ss[2*c + 1] = ldext(bet, gO + c, f32) - mu*sc;
}

// ---- fused GRU + LayerNorm: hout = LN((1-z)*tanh(gn + r*hn) + z*h) ----------
// 4 single-acc passes (R5 structure, no spill) with 64x32 wave tiles.
__global__ __launch_bounds__(512, 2) void k_gru(
    const u16* __restrict__ Gp, const u16* __restrict__ hp,
    const u16* __restrict__ wihl, const u16* __restrict__ whhl,
    const void* __restrict__ bih, const void* __restrict__ bhh, long bo,
    const void* __restrict__ lng, const void* __restrict__ lnb,
    const float* __restrict__ ss, u16* __restrict__ hout,
    const int* __restrict__ dflag)
{
  const bool f32 = (*dflag != 0);
  __shared__ u16 Ag[64*256];
  __shared__ u16 Ah[64*256];
  const int tid = threadIdx.x;
  const size_t rowBase = (size_t)blockIdx.x * 64;
  const int lane = tid & 63, wave = tid >> 6;
  const int wc = wave * 32;
  const int fr = lane & 15, quad = lane >> 4;

  stage_tile64_bn(Gp, Ag, rowBase, tid, ss);   // Ag = BN(G)  (g input)
  stage_tile64(hp, Ah, rowBase, tid);
  __syncthreads();

  f32x4 acc[4][2];
  unsigned pk[4][2][2];                   // packed bf16 intermediate (2 vals/u32)

  // stage 1: hn = h@Whn^T + bhh_n  -> pk
  ZERO_ACC42(acc);
  gate_gemm<256>(acc, Ah, nullptr, whhl + 512*256, nullptr, wc, fr, quad);
  #pragma unroll
  for (int ni=0;ni<2;ni++){
    const float bv = ldext(bhh, bo + 512 + wc + ni*16 + fr, f32);
    #pragma unroll
    for (int mi=0;mi<4;mi++)
      #pragma unroll
      for (int q=0;q<2;q++)
        pk[mi][ni][q] = (unsigned)f2bf(acc[mi][ni][2*q] + bv)
                      | ((unsigned)f2bf(acc[mi][ni][2*q+1] + bv) << 16);
  }

  // stage 2: r = sigm([g|h]@[Wir|Whr]^T + bir + bhr); pk <- r*hn
  ZERO_ACC42(acc);
  gate_gemm<512>(acc, Ag, Ah, wihl, whhl, wc, fr, quad);
  #pragma unroll
  for (int ni=0;ni<2;ni++){
    const int col = wc + ni*16 + fr;
    const float bv = ldext(bih, bo + col, f32) + ldext(bhh, bo + col, f32);
    #pragma unroll
    for (int mi=0;mi<4;mi++)
      #pragma unroll
      for (int q=0;q<2;q++){
        float h0 = bf2f((u16)(pk[mi][ni][q] & 0xFFFFu));
        float h1 = bf2f((u16)(pk[mi][ni][q] >> 16));
        float r0 = fsigm(acc[mi][ni][2*q]   + bv);
        float r1 = fsigm(acc[mi][ni][2*q+1] + bv);
        pk[mi][ni][q] = (unsigned)f2bf(r0*h0) | ((unsigned)f2bf(r1*h1) << 16);
      }
  }

  // stage 3: n = tanh(g@Win^T + bin + r*hn); pk <- n
  ZERO_ACC42(acc);
  gate_gemm<256>(acc, Ag, nullptr, wihl + 512*256, nullptr, wc, fr, quad);
  #pragma unroll
  for (int ni=0;ni<2;ni++){
    const float bv = ldext(bih, bo + 512 + wc + ni*16 + fr, f32);
    #pragma unroll
    for (int mi=0;mi<4;mi++)
      #pragma unroll
      for (int q=0;q<2;q++){
        float n0 = ftanh(acc[mi][ni][2*q]   + bv + bf2f((u16)(pk[mi][ni][q] & 0xFFFFu)));
        float n1 = ftanh(acc[mi][ni][2*q+1] + bv + bf2f((u16)(pk[mi][ni][q] >> 16)));
        pk[mi][ni][q] = (unsigned)f2bf(n0) | ((unsigned)f2bf(n1) << 16);
      }
  }

  // stage 4: z = sigm([g|h]@[Wiz|Whz]^T + biz + bhz); pk <- (1-z)*n + z*h
  ZERO_ACC42(acc);
  gate_gemm<512>(acc, Ag, Ah, wihl + 256*256, whhl + 256*256, wc, fr, quad);
  #pragma unroll
  for (int ni=0;ni<2;ni++){
    const int col = wc + ni*16 + fr;
    const float bv = ldext(bih, bo + 256 + col, f32) + ldext(bhh, bo + 256 + col, f32);
    #pragma unroll
    for (int mi=0;mi<4;mi++)
      #pragma unroll
      for (int q=0;q<2;q++){
        const int row0 = mi*16 + quad*4 + 2*q;
        const unsigned pv = pk[mi][ni][q];
        float v0, v1;
        {
          const float z = fsigm(acc[mi][ni][2*q] + bv);
          const float hval = bf2f(*(const u16*)((const char*)Ah + swzb(row0, col*2)));
          v0 = (1.f - z)*bf2f((u16)(pv & 0xFFFFu)) + z*hval;
        }
        {
          const float z = fsigm(acc[mi][ni][2*q+1] + bv);
          const float hval = bf2f(*(const u16*)((const char*)Ah + swzb(row0+1, col*2)));
          v1 = (1.f - z)*bf2f((u16)(pv >> 16)) + z*hval;
        }
        pk[mi][ni][q] = (unsigned)f2bf(v0) | ((unsigned)f2bf(v1) << 16);
      }
  }

  // ---- route hnew through LDS; two-pass LayerNorm (minimal live registers) --
  __syncthreads();                        // all waves done reading Ag/Ah
  #pragma unroll
  for (int ni=0;ni<2;ni++){
    const int col = wc + ni*16 + fr;
    #pragma unroll
    for (int mi=0;mi<4;mi++)
      #pragma unroll
      for (int q=0;q<2;q++){
        const int row0 = mi*16 + quad*4 + 2*q;
        const unsigned pv = pk[mi][ni][q];
        *(u16*)((char*)Ag + swzb(row0,   col*2)) = (u16)(pv & 0xFFFFu);
        *(u16*)((char*)Ag + swzb(row0+1, col*2)) = (u16)(pv >> 16);
      }
  }
  __syncthreads();

  // 8 threads per row, 32 cols each. Pass 1: stats only (2 live floats).
  const int erow = tid >> 3, seg = tid & 7;
  float s1 = 0.f, s2 = 0.f;
  #pragma unroll
  for (int jj=0;jj<8;jj++){
    uint2 w = *(const uint2*)((const char*)Ag + swzb(erow, seg*64 + jj*8));
    float v0 = bf2f((u16)(w.x & 0xFFFFu)), v1 = bf2f((u16)(w.x >> 16));
    float v2 = bf2f((u16)(w.y & 0xFFFFu)), v3 = bf2f((u16)(w.y >> 16));
    s1 += v0 + v1 + v2 + v3;
    s2 += v0*v0 + v1*v1 + v2*v2 + v3*v3;
  }
  s1 += __shfl_xor(s1, 1); s2 += __shfl_xor(s2, 1);
  s1 += __shfl_xor(s1, 2); s2 += __shfl_xor(s2, 2);
  s1 += __shfl_xor(s1, 4); s2 += __shfl_xor(s2, 4);
  const float mu   = s1 * (1.f/256.f);
  const float var  = s2 * (1.f/256.f) - mu*mu;
  const float rstd = rsqrtf(fmaxf(var, 0.f) + LN_EPS);

  // Pass 2: re-read LDS, normalize, store.
  const size_t rb = (rowBase + erow)*256 + (size_t)seg*32;
  #pragma unroll
  for (int jj=0;jj<8;jj++){
    uint2 w = *(const uint2*)((const char*)Ag + swzb(erow, seg*64 + jj*8));
    const long c0 = seg*32 + jj*4;
    float v0 = (bf2f((u16)(w.x & 0xFFFFu)) - mu)*rstd*ldext(lng, c0+0, f32) + ldext(lnb, c0+0, f32);
    float v1 = (bf2f((u16)(w.x >> 16))     - mu)*rstd*ldext(lng, c0+1, f32) + ldext(lnb, c0+1, f32);
    float v2 = (bf2f((u16)(w.y & 0xFFFFu)) - mu)*rstd*ldext(lng, c0+2, f32) + ldext(lnb, c0+2, f32);
    float v3 = (bf2f((u16)(w.y >> 16))     - mu)*rstd*ldext(lng, c0+3, f32) + ldext(lnb, c0+3, f32);
    *(ushort4*)&hout[rb + jj*4] = make_ushort4(f2bf(v0), f2bf(v1), f2bf(v2), f2bf(v3));
  }
}

// ---- fused segment max: h0/h1/h2 maxima + m=h0*h1*h2, e=h0+h1+h2 maxima -----
// One wave per graph; lane covers 4 consecutive cols. One pass over 3 planes.
__global__ __launch_bounds__(256) void k_segmax_all(
    const u16* __restrict__ h0, const u16* __restrict__ h1,
    const u16* __restrict__ h2, void* __restrict__ out,
    const int* __restrict__ batch, const int* __restrict__ dflag)
{
  const bool f32 = (*dflag != 0);
  const int g = blockIdx.x*4 + (threadIdx.x >> 6);
  const int lane = threadIdx.x & 63;
  int lo = 0, hi = N_NODES;
  while (lo < hi){ int mid = (lo + hi) >> 1; if (batch[mid] < g) lo = mid + 1; else hi = mid; }
  const int s = lo;
  hi = N_NODES;
  while (lo < hi){ int mid = (lo + hi) >> 1; if (batch[mid] < g + 1) lo = mid + 1; else hi = mid; }
  const int epos = lo;

  const float NINF = __uint_as_float(0xFF800000u);
  float x0[4], x1[4], x2[4], mm[4], ee[4];
  #pragma unroll
  for (int j=0;j<4;j++){ x0[j]=NINF; x1[j]=NINF; x2[j]=NINF; mm[j]=NINF; ee[j]=NINF; }
  for (int r = s; r < epos; r++){
    const size_t rb = (size_t)r*256 + lane*4;
    ushort4 a = *(const ushort4*)&h0[rb];
    ushort4 b = *(const ushort4*)&h1[rb];
    ushort4 c = *(const ushort4*)&h2[rb];
    float av[4] = {bf2f(a.x),bf2f(a.y),bf2f(a.z),bf2f(a.w)};
    float bv[4] = {bf2f(b.x),bf2f(b.y),bf2f(b.z),bf2f(b.w)};
    float cv[4] = {bf2f(c.x),bf2f(c.y),bf2f(c.z),bf2f(c.w)};
    #pragma unroll
    for (int j=0;j<4;j++){
      x0[j] = fmaxf(x0[j], av[j]);
      x1[j] = fmaxf(x1[j], bv[j]);
      x2[j] = fmaxf(x2[j], cv[j]);
      mm[j] = fmaxf(mm[j], av[j]*bv[j]*cv[j]);
      ee[j] = fmaxf(ee[j], av[j]+bv[j]+cv[j]);
    }
  }
  const long ob = (long)g*1280 + lane*4;
  if (f32){
    float* o = (float*)out;
    #pragma unroll
    for (int j=0;j<4;j++){
      o[ob +        j] = x0[j];
      o[ob +  256 + j] = x1[j];
      o[ob +  512 + j] = x2[j];
      o[ob +  768 + j] = mm[j];
      o[ob + 1024 + j] = ee[j];
    }
  } else {
    u16* o = (u16*)out;
    *(ushort4*)&o[ob]        = make_ushort4(f2bf(x0[0]), f2bf(x0[1]), f2bf(x0[2]), f2bf(x0[3]));
    *(ushort4*)&o[ob +  256] = make_ushort4(f2bf(x1[0]), f2bf(x1[1]), f2bf(x1[2]), f2bf(x1[3]));
    *(ushort4*)&o[ob +  512] = make_ushort4(f2bf(x2[0]), f2bf(x2[1]), f2bf(x2[2]), f2bf(x2[3]));
    *(ushort4*)&o[ob +  768] = make_ushort4(f2bf(mm[0]), f2bf(mm[1]), f2bf(mm[2]), f2bf(mm[3]));
    *(ushort4*)&o[ob + 1024] = make_ushort4(f2bf(ee[0]), f2bf(ee[1]), f2bf(ee[2]), f2bf(ee[3]));
  }
}

// ---- launcher ---------------------------------------------------------------
extern "C" void kernel_launch(void* const* d_in, const int* in_sizes, int n_in,
                              void* d_out, int out_size, void* d_ws, size_t ws_size,
                              hipStream_t stream)
{
  const void* x   = d_in[0];
  const void* l1w = d_in[1];  const void* l1b = d_in[2];
  const void* l2w = d_in[3];  const void* l2b = d_in[4];
  const void* bng = d_in[5];  const void* bnb = d_in[6];
  const void* wih = d_in[7];  const void* whh = d_in[8];
  const void* bih = d_in[9];  const void* bhh = d_in[10];
  const void* lng = d_in[11]; const void* lnb = d_in[12];
  const int* ei    = (const int*)d_in[13];
  const int* batch = (const int*)d_in[14];
  (void)in_sizes; (void)n_in; (void)out_size; (void)ws_size;

  const size_t PL = S_EL * 2;            // bf16 plane bytes (51.25 MB)
  char* p = (char*)d_ws; size_t off = 0;
  auto take = [&](size_t b){ void* q = p + off; off += (b + 255) & ~(size_t)255; return q; };
  u16*      hx   = (u16*)take(PL);       // x (bf16) -> also reused as h2 output
  u16*      hA   = (u16*)take(PL);       // h0
  u16*      hB   = (u16*)take(PL);       // h1
  u16*      G    = (u16*)take(PL);       // agg -> g0 -> g
  float*    bns  = (float*)take(512*4);
  float*    bss  = (float*)take(512*4);  // BN scale/shift interleaved
  int*      dflg = (int*)take(256);
  int*      cnt  = (int*)take((size_t)N_NODES*4);
  int*      bkt  = (int*)take((size_t)N_NODES*CAP*4);   // 12.8 MB
  int*      ovf  = (int*)take((size_t)N_EDGES*4);       // worst-case overflow list
  int*      ovfc = (int*)take(256);
  // bf16 weight copies (all layers): lin1|lin2: 3*64K, wih|whh: 3*192K elems
  u16*      wb1  = (u16*)take((size_t)3*65536*2);
  u16*      wb2  = (u16*)take((size_t)3*65536*2);
  u16*      wbih = (u16*)take((size_t)3*196608*2);
  u16*      wbhh = (u16*)take((size_t)3*196608*2);

  k_detect<<<1, 64, 0, stream>>>((const unsigned*)x, dflg);
  hipMemsetAsync(cnt, 0, (size_t)N_NODES*4, stream);
  hipMemsetAsync(ovfc, 0, 4, stream);
  k_h_init <<<S_EL/8/256, 256, 0, stream>>>(x, hx, dflg);
  k_bucket_build<<<(N_EDGES + 255)/256, 256, 0, stream>>>(ei, cnt, bkt, ovf, ovfc);
  k_wconv<<< 96, 256, 0, stream>>>(l1w, wb1,  dflg);   // 3*65536/8/256
  k_wconv<<< 96, 256, 0, stream>>>(l2w, wb2,  dflg);
  k_wconv<<<288, 256, 0, stream>>>(wih, wbih, dflg);   // 3*196608/8/256
  k_wconv<<<288, 256, 0, stream>>>(whh, wbhh, dflg);

  const u16* hin[3]  = {hx, hA, hB};
  u16*       hout[3] = {hA, hB, hx};     // hx dead after layer-0 staging

  for (int l = 0; l < 3; l++){
    const long bo = (long)l*768;
    hipMemsetAsync(bns, 0, 512*4, stream);
    k_gather<<<(M_PAD*128)/256, 256, 0, stream>>>((const unsigned*)hin[l], cnt, bkt, (unsigned*)G);
    k_ovf_scatter<<<512, 256, 0, stream>>>((const unsigned*)hin[l], ei, ovf, ovfc, (unsigned*)G);

    // fused MLP (lin1+relu+lin2+relu) in-place on G, with fused BN stats
    k_mlp<<<N_TILES*2, 512, 0, stream>>>(G, wb1 + (size_t)l*65536, l1b,
                                         wb2 + (size_t)l*65536, l2b,
                                         (long)l*256, bns, dflg);
    k_bn_fin<<<1, 256, 0, stream>>>(bns, bng, bnb, (long)l*256, bss, dflg);

    // fused GRU + LayerNorm, full grid, h plane rotation
    k_gru<<<N_TILES*2, 512, 0, stream>>>(G, hin[l],
                                         wbih + (size_t)l*196608, wbhh + (size_t)l*196608,
                                         bih, bhh, bo, lng, lnb, bss, hout[l], dflg);
  }
  // all 5 output slices in one pass over the three h planes
  k_segmax_all<<<N_GRAPH/4, 256, 0, stream>>>(hA, hB, hx, d_out, batch, dflg);
}